// Round 1
// baseline (1142.929 us; speedup 1.0000x reference)
//
#include <hip/hip_runtime.h>

#define N_ROWS 65536
#define DIM    512
#define K_CENT 4096
#define TILE_M 128
#define TILE_N 128
#define BK     32
#define KSTEPS (DIM / BK)        // 16
#define NKT    (K_CENT / TILE_N) // 32
#define MARGIN 6.0f
#define CAND_CAP 3072

typedef _Float16 half8 __attribute__((ext_vector_type(8)));
typedef float floatx4 __attribute__((ext_vector_type(4)));

// order-preserving float<->uint map (works for negatives too)
__device__ __forceinline__ unsigned mapF(float f) {
  unsigned u = __float_as_uint(f);
  return (u & 0x80000000u) ? ~u : (u | 0x80000000u);
}
__device__ __forceinline__ float unmapF(unsigned m) {
  unsigned u = (m & 0x80000000u) ? (m ^ 0x80000000u) : ~m;
  return __uint_as_float(u);
}

__device__ __forceinline__ void gload_lds16(const void* g, void* l) {
  __builtin_amdgcn_global_load_lds(
      (const __attribute__((address_space(1))) void*)g,
      (__attribute__((address_space(3))) void*)l, 16, 0, 0);
}

__global__ void prep_convert(const float* __restrict__ x, const float* __restrict__ c,
                             _Float16* __restrict__ xh, _Float16* __restrict__ ch) {
  const size_t nx = (size_t)N_ROWS * DIM;
  const size_t nc = (size_t)K_CENT * DIM;
  size_t i = ((size_t)blockIdx.x * blockDim.x + threadIdx.x) * 8;
  if (i >= nx + nc) return;
  const float* src;
  _Float16* dst;
  if (i < nx) { src = x + i; dst = xh + i; }
  else        { src = c + (i - nx); dst = ch + (i - nx); }
  floatx4 a = *(const floatx4*)src;
  floatx4 b = *(const floatx4*)(src + 4);
  half8 h;
#pragma unroll
  for (int e = 0; e < 4; ++e) { h[e] = (_Float16)a[e]; h[4 + e] = (_Float16)b[e]; }
  *(half8*)dst = h;
}

// 256 threads = 4 waves (2x2), block tile 128 rows x 128 centers, wave tile 64x64,
// 16x16x32 f16 MFMA, BK=32. Two passes over K (screen-min, then candidate collect),
// then fp64-exact refinement of ~2 candidates/row.
template <bool PRE>
__global__ __launch_bounds__(256)
void kmeans_argmin(const float* __restrict__ x, const float* __restrict__ cent,
                   const _Float16* __restrict__ xh, const _Float16* __restrict__ ch,
                   int* __restrict__ out) {
  __shared__ _Float16 ldsA[TILE_M][BK];
  __shared__ _Float16 ldsB[TILE_N][BK];
  __shared__ float csq2[TILE_N][2];       // deterministic 2-slot ||c||^2 accum
  __shared__ unsigned sminU[TILE_M];
  __shared__ float thrS[TILE_M];
  __shared__ unsigned long long best[TILE_M];
  __shared__ unsigned cand[CAND_CAP];
  __shared__ int candCount;

  const int t = threadIdx.x;
  const int lane = t & 63;
  const int wave = t >> 6;
  const int wm = wave >> 1;
  const int wn = wave & 1;
  const int quad = lane >> 4;
  const int l15 = lane & 15;
  const int rowBlock = blockIdx.x * TILE_M;

  float runmin[4][4];
#pragma unroll
  for (int a = 0; a < 4; ++a)
#pragma unroll
    for (int b = 0; b < 4; ++b) runmin[a][b] = 3.4e38f;

  float thrR[4][4];

  for (int pass = 0; pass < 2; ++pass) {
    for (int kt = 0; kt < NKT; ++kt) {
      const int ktBase = kt * TILE_N;
      csq2[t >> 1][t & 1] = 0.f;   // own slot; prev-kt readers are behind a barrier
      floatx4 acc[4][4];
#pragma unroll
      for (int fm = 0; fm < 4; ++fm)
#pragma unroll
        for (int fn = 0; fn < 4; ++fn) acc[fm][fn] = (floatx4){0.f, 0.f, 0.f, 0.f};

      for (int ks = 0; ks < KSTEPS; ++ks) {
        const int kd = ks * BK;
        if (PRE) {
          // async fp16 global->LDS, 16B/lane, lane-contiguous row-major [128][32]
#pragma unroll
          for (int h = 0; h < 2; ++h) {
            int chunk = h * 256 + wave * 64 + lane;
            int r = chunk >> 2, c0 = (chunk & 3) << 3;
            gload_lds16(xh + (size_t)(rowBlock + r) * DIM + kd + c0,
                        (char*)&ldsA[0][0] + (size_t)(h * 256 + wave * 64) * 16);
          }
#pragma unroll
          for (int h = 0; h < 2; ++h) {
            int chunk = h * 256 + wave * 64 + lane;
            int r = chunk >> 2, c0 = (chunk & 3) << 3;
            gload_lds16(ch + (size_t)(ktBase + r) * DIM + kd + c0,
                        (char*)&ldsB[0][0] + (size_t)(h * 256 + wave * 64) * 16);
          }
        } else {
          // fp32 loads + convert + ds_write (no big ws available)
          const int r = t >> 1, c0 = (t & 1) << 4;
          const float* gA = x + (size_t)(rowBlock + r) * DIM + kd + c0;
          const float* gB = cent + (size_t)(ktBase + r) * DIM + kd + c0;
          floatx4 a0 = *(const floatx4*)(gA);
          floatx4 a1 = *(const floatx4*)(gA + 4);
          floatx4 a2 = *(const floatx4*)(gA + 8);
          floatx4 a3 = *(const floatx4*)(gA + 12);
          floatx4 b0 = *(const floatx4*)(gB);
          floatx4 b1 = *(const floatx4*)(gB + 4);
          floatx4 b2 = *(const floatx4*)(gB + 8);
          floatx4 b3 = *(const floatx4*)(gB + 12);
          half8 ha0, ha1, hb0, hb1;
#pragma unroll
          for (int e = 0; e < 4; ++e) {
            ha0[e] = (_Float16)a0[e]; ha0[4 + e] = (_Float16)a1[e];
            ha1[e] = (_Float16)a2[e]; ha1[4 + e] = (_Float16)a3[e];
            hb0[e] = (_Float16)b0[e]; hb0[4 + e] = (_Float16)b1[e];
            hb1[e] = (_Float16)b2[e]; hb1[4 + e] = (_Float16)b3[e];
          }
          *(half8*)&ldsA[r][c0] = ha0;
          *(half8*)&ldsA[r][c0 + 8] = ha1;
          *(half8*)&ldsB[r][c0] = hb0;
          *(half8*)&ldsB[r][c0 + 8] = hb1;
        }
        __syncthreads();

        // ||c||^2 partial from the staged fp16 tile (consistent across passes)
        {
          const int r = t >> 1, c0 = (t & 1) << 4;
          half8 b0 = *(const half8*)&ldsB[r][c0];
          half8 b1 = *(const half8*)&ldsB[r][c0 + 8];
          float s = 0.f;
#pragma unroll
          for (int e = 0; e < 8; ++e) {
            float v0 = (float)b0[e], v1 = (float)b1[e];
            s += v0 * v0 + v1 * v1;
          }
          csq2[r][t & 1] += s;
        }

        // fragment loads + 16 MFMA
        half8 af[4], bf[4];
#pragma unroll
        for (int fm = 0; fm < 4; ++fm)
          af[fm] = *(const half8*)&ldsA[wm * 64 + fm * 16 + l15][quad * 8];
#pragma unroll
        for (int fn = 0; fn < 4; ++fn)
          bf[fn] = *(const half8*)&ldsB[wn * 64 + fn * 16 + l15][quad * 8];
#pragma unroll
        for (int fm = 0; fm < 4; ++fm)
#pragma unroll
          for (int fn = 0; fn < 4; ++fn)
            acc[fm][fn] = __builtin_amdgcn_mfma_f32_16x16x32_f16(af[fm], bf[fn], acc[fm][fn], 0, 0, 0);
        __syncthreads();
      }

      // epilogue: s = ||c||^2 - 2*cross  (||x||^2 omitted: constant per row)
      // C layout 16x16: col = lane&15, row = quad*4 + e  [m89-verified]
      if (pass == 0) {
#pragma unroll
        for (int fn = 0; fn < 4; ++fn) {
          int cl = wn * 64 + fn * 16 + l15;
          float cs = csq2[cl][0] + csq2[cl][1];
#pragma unroll
          for (int fm = 0; fm < 4; ++fm)
#pragma unroll
            for (int e = 0; e < 4; ++e) {
              float s = cs - 2.f * acc[fm][fn][e];
              runmin[fm][e] = fminf(runmin[fm][e], s);
            }
        }
      } else {
#pragma unroll
        for (int fn = 0; fn < 4; ++fn) {
          int cl = wn * 64 + fn * 16 + l15;
          float cs = csq2[cl][0] + csq2[cl][1];
          int k = ktBase + cl;
#pragma unroll
          for (int fm = 0; fm < 4; ++fm)
#pragma unroll
            for (int e = 0; e < 4; ++e) {
              float s = cs - 2.f * acc[fm][fn][e];
              if (s <= thrR[fm][e]) {
                int idx = atomicAdd(&candCount, 1);
                if (idx < CAND_CAP) {
                  int rl = wm * 64 + fm * 16 + quad * 4 + e;
                  cand[idx] = ((unsigned)k << 7) | (unsigned)rl;
                }
              }
            }
        }
      }
      __syncthreads();
    }

    if (pass == 0) {
      if (t < TILE_M) sminU[t] = 0xFFFFFFFFu;
      if (t < TILE_M) best[t] = ~0ull;
      if (t == 0) candCount = 0;
      __syncthreads();
#pragma unroll
      for (int fm = 0; fm < 4; ++fm)
#pragma unroll
        for (int e = 0; e < 4; ++e) {
          int rl = wm * 64 + fm * 16 + quad * 4 + e;
          atomicMin(&sminU[rl], mapF(runmin[fm][e]));
        }
      __syncthreads();
      if (t < TILE_M) thrS[t] = unmapF(sminU[t]) + MARGIN;
      __syncthreads();
#pragma unroll
      for (int fm = 0; fm < 4; ++fm)
#pragma unroll
        for (int e = 0; e < 4; ++e)
          thrR[fm][e] = thrS[wm * 64 + fm * 16 + quad * 4 + e];
    }
  }

  // fp64-exact refinement: 16 lanes per candidate, original fp32 inputs
  __syncthreads();
  int cnt = candCount;
  if (cnt > CAND_CAP) cnt = CAND_CAP;
  const int g = t >> 4;   // 16 groups of 16 lanes
  const int sl = t & 15;
  for (int ci = g; ci < cnt; ci += 16) {
    unsigned cd = cand[ci];
    int rl = cd & 127;
    int k = cd >> 7;
    const float* xr = x + (size_t)(rowBlock + rl) * DIM;
    const float* cr = cent + (size_t)k * DIM;
    double d = 0.0;
#pragma unroll
    for (int j = 0; j < DIM / 64; ++j) {
      floatx4 xv = *(const floatx4*)(xr + j * 64 + sl * 4);
      floatx4 cv = *(const floatx4*)(cr + j * 64 + sl * 4);
#pragma unroll
      for (int e = 0; e < 4; ++e) {
        double df = (double)xv[e] - (double)cv[e];
        d += df * df;
      }
    }
#pragma unroll
    for (int off = 1; off < 16; off <<= 1) d += __shfl_xor(d, off, 64);
    if (sl == 0) {
      // positive doubles order as uint64; low 12 mantissa bits -> index (ties: lower k wins)
      unsigned long long key =
          ((unsigned long long)__double_as_longlong(d) & ~0xFFFull) | (unsigned long long)k;
      atomicMin(&best[rl], key);
    }
  }
  __syncthreads();
  if (t < TILE_M) out[rowBlock + t] = (int)(best[t] & 0xFFFull);
}

extern "C" void kernel_launch(void* const* d_in, const int* in_sizes, int n_in,
                              void* d_out, int out_size, void* d_ws, size_t ws_size,
                              hipStream_t stream) {
  const float* x = (const float*)d_in[0];
  const float* cent = (const float*)d_in[1];
  int* out = (int*)d_out;
  const size_t needWs = ((size_t)N_ROWS + K_CENT) * DIM * sizeof(_Float16);  // ~68 MB
  if (ws_size >= needWs) {
    _Float16* xh = (_Float16*)d_ws;
    _Float16* ch = xh + (size_t)N_ROWS * DIM;
    const size_t total8 = ((size_t)N_ROWS + K_CENT) * DIM / 8;
    prep_convert<<<(unsigned)((total8 + 255) / 256), 256, 0, stream>>>(x, cent, xh, ch);
    kmeans_argmin<true><<<N_ROWS / TILE_M, 256, 0, stream>>>(x, cent, xh, ch, out);
  } else {
    kmeans_argmin<false><<<N_ROWS / TILE_M, 256, 0, stream>>>(x, cent, nullptr, nullptr, out);
  }
}

// Round 2
// 740.677 us; speedup vs baseline: 1.5431x; 1.5431x over previous
//
#include <hip/hip_runtime.h>

#define N_ROWS 65536
#define DIM    512
#define K_CENT 4096
#define TILE_M 128
#define TILE_N 128
#define BK     32
#define KSTEPS (DIM / BK)        // 16
#define NKT    (K_CENT / TILE_N) // 32
#define THREADS 512
#define MARGIN 6.0f
#define CAND_CAP 3072
#define COMPACT_TRIG 2048

typedef _Float16 half8 __attribute__((ext_vector_type(8)));
typedef float floatx4 __attribute__((ext_vector_type(4)));

// order-preserving float<->uint map
__device__ __forceinline__ unsigned mapF(float f) {
  unsigned u = __float_as_uint(f);
  return (u & 0x80000000u) ? ~u : (u | 0x80000000u);
}
__device__ __forceinline__ float unmapF(unsigned m) {
  unsigned u = (m & 0x80000000u) ? (m ^ 0x80000000u) : ~m;
  return __uint_as_float(u);
}

__device__ __forceinline__ void gload_lds16(const void* g, void* l) {
  __builtin_amdgcn_global_load_lds(
      (const __attribute__((address_space(1))) void*)g,
      (__attribute__((address_space(3))) void*)l, 16, 0, 0);
}

__global__ void prep_convert(const float* __restrict__ x, const float* __restrict__ c,
                             _Float16* __restrict__ xh, _Float16* __restrict__ ch) {
  const size_t nx = (size_t)N_ROWS * DIM;
  const size_t nc = (size_t)K_CENT * DIM;
  size_t i = ((size_t)blockIdx.x * blockDim.x + threadIdx.x) * 8;
  if (i >= nx + nc) return;
  const float* src;
  _Float16* dst;
  if (i < nx) { src = x + i; dst = xh + i; }
  else        { src = c + (i - nx); dst = ch + (i - nx); }
  floatx4 a = *(const floatx4*)src;
  floatx4 b = *(const floatx4*)(src + 4);
  half8 h;
#pragma unroll
  for (int e = 0; e < 4; ++e) { h[e] = (_Float16)a[e]; h[4 + e] = (_Float16)b[e]; }
  *(half8*)dst = h;
}

// one wave per center row: csq[k] = sum((fp16 c)^2) in fp32
__global__ void prep_csq(const _Float16* __restrict__ ch, float* __restrict__ csqg) {
  int w = (int)((blockIdx.x * blockDim.x + threadIdx.x) >> 6);
  int lane = threadIdx.x & 63;
  if (w >= K_CENT) return;
  half8 h = *(const half8*)(ch + (size_t)w * DIM + lane * 8);
  float s = 0.f;
#pragma unroll
  for (int e = 0; e < 8; ++e) { float v = (float)h[e]; s += v * v; }
#pragma unroll
  for (int off = 1; off < 64; off <<= 1) s += __shfl_xor(s, off, 64);
  if (lane == 0) csqg[w] = s;
}

// MODE 0: no ws (fp32 loads, on-the-fly convert, LDS csq)
// MODE 1: fp16 pre-converted in ws, LDS csq
// MODE 2: fp16 pre-converted + precomputed csq in ws
//
// 512 threads = 8 waves (4 wave-rows x 2 wave-cols), block tile 128x128,
// wave tile 32x64, 16x16x32 f16 MFMA, BK=32. SINGLE pass over K with
// prefix-min candidate collection (stale-threshold superset property),
// LDS compaction backstop, fp64-exact refine of survivors.
// XOR chunk swizzle ((row>>1)&3) kills the 8-way ds_read_b128 bank conflict
// while staying compatible with global_load_lds's lane-contiguous dst.
template <int MODE>
__global__ __launch_bounds__(THREADS, 4)
void kmeans_argmin(const float* __restrict__ x, const float* __restrict__ cent,
                   const _Float16* __restrict__ xh, const _Float16* __restrict__ ch,
                   const float* __restrict__ csqg, int* __restrict__ out) {
  __shared__ _Float16 ldsA[TILE_M * BK];
  __shared__ _Float16 ldsB[TILE_N * BK];
  __shared__ float csq4[TILE_N][4];
  __shared__ unsigned sminU[TILE_M];
  __shared__ unsigned long long best[TILE_M];
  __shared__ unsigned candKey[CAND_CAP];
  __shared__ float candS[CAND_CAP];
  __shared__ int candCount;

  char* ldsAc = (char*)ldsA;
  char* ldsBc = (char*)ldsB;

  const int t = threadIdx.x;
  const int lane = t & 63;
  const int wave = t >> 6;   // 0..7
  const int wm = wave >> 1;  // 0..3 row-waves
  const int wn = wave & 1;   // 0..1 col-waves
  const int quad = lane >> 4;
  const int l15 = lane & 15;
  const int rowBlock = blockIdx.x * TILE_M;

  if (t < TILE_M) { sminU[t] = 0xFFFFFFFFu; best[t] = ~0ull; }
  if (t == 0) candCount = 0;

  // staging mapping: thread t owns LDS slot t (16B chunks); swizzled source chunk
  const int sr = t >> 2;
  const int sck = (t & 3) ^ ((sr >> 1) & 3);

  float thrR[2][4];

  for (int kt = 0; kt < NKT; ++kt) {
    const int ktBase = kt * TILE_N;
    if (MODE <= 1) csq4[t >> 2][t & 3] = 0.f;  // safe: prev-kt readers behind end-of-kt barrier
    floatx4 acc[2][4];
#pragma unroll
    for (int fm = 0; fm < 2; ++fm)
#pragma unroll
      for (int fn = 0; fn < 4; ++fn) acc[fm][fn] = (floatx4){0.f, 0.f, 0.f, 0.f};

    for (int ks = 0; ks < KSTEPS; ++ks) {
      const int kd = ks * BK;
      if (MODE >= 1) {
        gload_lds16(xh + (size_t)(rowBlock + sr) * DIM + kd + sck * 8,
                    ldsAc + (size_t)wave * 1024);
        gload_lds16(ch + (size_t)(ktBase + sr) * DIM + kd + sck * 8,
                    ldsBc + (size_t)wave * 1024);
        __syncthreads();
        if (MODE == 1) {
          half8 hb = *(const half8*)(ldsBc + (size_t)t * 16);
          float s = 0.f;
#pragma unroll
          for (int e = 0; e < 8; ++e) { float v = (float)hb[e]; s += v * v; }
          csq4[sr][t & 3] += s;
        }
      } else {
        const float* gA = x + (size_t)(rowBlock + sr) * DIM + kd + sck * 8;
        const float* gB = cent + (size_t)(ktBase + sr) * DIM + kd + sck * 8;
        floatx4 a0 = *(const floatx4*)gA, a1 = *(const floatx4*)(gA + 4);
        floatx4 b0 = *(const floatx4*)gB, b1 = *(const floatx4*)(gB + 4);
        half8 ha, hb;
        float s = 0.f;
#pragma unroll
        for (int e = 0; e < 4; ++e) {
          ha[e] = (_Float16)a0[e]; ha[4 + e] = (_Float16)a1[e];
          hb[e] = (_Float16)b0[e]; hb[4 + e] = (_Float16)b1[e];
        }
#pragma unroll
        for (int e = 0; e < 8; ++e) { float v = (float)hb[e]; s += v * v; }
        *(half8*)(ldsAc + (size_t)t * 16) = ha;
        *(half8*)(ldsBc + (size_t)t * 16) = hb;
        csq4[sr][t & 3] += s;
        __syncthreads();
      }

      half8 af[2], bf[4];
#pragma unroll
      for (int fm = 0; fm < 2; ++fm) {
        int row = wm * 32 + fm * 16 + l15;
        int slot = (row << 2) | (quad ^ ((row >> 1) & 3));
        af[fm] = *(const half8*)(ldsAc + slot * 16);
      }
#pragma unroll
      for (int fn = 0; fn < 4; ++fn) {
        int cl = wn * 64 + fn * 16 + l15;
        int slot = (cl << 2) | (quad ^ ((cl >> 1) & 3));
        bf[fn] = *(const half8*)(ldsBc + slot * 16);
      }
#pragma unroll
      for (int fm = 0; fm < 2; ++fm)
#pragma unroll
        for (int fn = 0; fn < 4; ++fn)
          acc[fm][fn] = __builtin_amdgcn_mfma_f32_16x16x32_f16(af[fm], bf[fn], acc[fm][fn], 0, 0, 0);
      __syncthreads();
    }

    // ---- epilogue: s = ||c||^2 - 2*cross (||x||^2 constant per row, dropped)
    // C layout 16x16: col = lane&15, row = quad*4 + e  [m89-verified]
    float cs[4];
#pragma unroll
    for (int fn = 0; fn < 4; ++fn) {
      int cl = wn * 64 + fn * 16 + l15;
      cs[fn] = (MODE == 2) ? csqg[ktBase + cl]
                           : (csq4[cl][0] + csq4[cl][1] + csq4[cl][2] + csq4[cl][3]);
    }
    float tmin[2][4];
#pragma unroll
    for (int fm = 0; fm < 2; ++fm)
#pragma unroll
      for (int e = 0; e < 4; ++e) tmin[fm][e] = 3.4e38f;
#pragma unroll
    for (int fn = 0; fn < 4; ++fn)
#pragma unroll
      for (int fm = 0; fm < 2; ++fm)
#pragma unroll
        for (int e = 0; e < 4; ++e) {
          float s = cs[fn] - 2.f * acc[fm][fn][e];
          tmin[fm][e] = fminf(tmin[fm][e], s);
        }

    if (kt == 0) {
      // seed threshold from tile 0's own minima before collecting tile 0
#pragma unroll
      for (int fm = 0; fm < 2; ++fm)
#pragma unroll
        for (int e = 0; e < 4; ++e)
          atomicMin(&sminU[wm * 32 + fm * 16 + quad * 4 + e], mapF(tmin[fm][e]));
      __syncthreads();
    }
#pragma unroll
    for (int fm = 0; fm < 2; ++fm)
#pragma unroll
      for (int e = 0; e < 4; ++e)
        thrR[fm][e] = unmapF(sminU[wm * 32 + fm * 16 + quad * 4 + e]) + MARGIN;

    // collect against (possibly stale) threshold — thr >= final thr, so superset
#pragma unroll
    for (int fn = 0; fn < 4; ++fn) {
      int k = ktBase + wn * 64 + fn * 16 + l15;
#pragma unroll
      for (int fm = 0; fm < 2; ++fm)
#pragma unroll
        for (int e = 0; e < 4; ++e) {
          float s = cs[fn] - 2.f * acc[fm][fn][e];
          if (s <= thrR[fm][e]) {
            int idx = atomicAdd(&candCount, 1);
            if (idx < CAND_CAP) {
              candKey[idx] = ((unsigned)k << 7) | (unsigned)(wm * 32 + fm * 16 + quad * 4 + e);
              candS[idx] = s;
            }
          }
        }
    }
    if (kt != 0) {
#pragma unroll
      for (int fm = 0; fm < 2; ++fm)
#pragma unroll
        for (int e = 0; e < 4; ++e)
          atomicMin(&sminU[wm * 32 + fm * 16 + quad * 4 + e], mapF(tmin[fm][e]));
    }
    __syncthreads();

    // compaction backstop against tightened threshold
    if (candCount > COMPACT_TRIG) {
      int cc = candCount; if (cc > CAND_CAP) cc = CAND_CAP;
      unsigned myK[6]; float myS[6]; int myN = 0;
      for (int i = t; i < cc; i += THREADS) {
        int rl = candKey[i] & 127;
        if (candS[i] <= unmapF(sminU[rl]) + MARGIN) {
          myK[myN] = candKey[i]; myS[myN] = candS[i]; ++myN;
        }
      }
      __syncthreads();
      if (t == 0) candCount = 0;
      __syncthreads();
      int base = atomicAdd(&candCount, myN);
      for (int j = 0; j < myN; ++j) { candKey[base + j] = myK[j]; candS[base + j] = myS[j]; }
      __syncthreads();
    }
  }

  // ---- fp64-exact refinement of surviving candidates (original fp32 inputs)
  int cnt = candCount; if (cnt > CAND_CAP) cnt = CAND_CAP;
  const int g = t >> 4;   // 32 groups of 16 lanes
  const int sl = t & 15;
  for (int ci = g; ci < cnt; ci += 32) {
    unsigned cd = candKey[ci];
    int rl = cd & 127;
    if (candS[ci] > unmapF(sminU[rl]) + MARGIN) continue;  // group-uniform branch
    int k = cd >> 7;
    const float* xr = x + (size_t)(rowBlock + rl) * DIM;
    const float* cr = cent + (size_t)k * DIM;
    double d = 0.0;
#pragma unroll
    for (int j = 0; j < DIM / 64; ++j) {
      floatx4 xv = *(const floatx4*)(xr + j * 64 + sl * 4);
      floatx4 cv = *(const floatx4*)(cr + j * 64 + sl * 4);
#pragma unroll
      for (int e = 0; e < 4; ++e) {
        double df = (double)xv[e] - (double)cv[e];
        d += df * df;
      }
    }
#pragma unroll
    for (int off = 1; off < 16; off <<= 1) d += __shfl_xor(d, off, 64);
    if (sl == 0) {
      // positive doubles order as uint64; low 12 mantissa bits -> index (ties: lower k)
      unsigned long long key =
          ((unsigned long long)__double_as_longlong(d) & ~0xFFFull) | (unsigned long long)k;
      atomicMin(&best[rl], key);
    }
  }
  __syncthreads();
  if (t < TILE_M) out[rowBlock + t] = (int)(best[t] & 0xFFFull);
}

extern "C" void kernel_launch(void* const* d_in, const int* in_sizes, int n_in,
                              void* d_out, int out_size, void* d_ws, size_t ws_size,
                              hipStream_t stream) {
  const float* x = (const float*)d_in[0];
  const float* cent = (const float*)d_in[1];
  int* out = (int*)d_out;
  const size_t nXh = (size_t)N_ROWS * DIM * sizeof(_Float16);   // 64 MiB
  const size_t nCh = (size_t)K_CENT * DIM * sizeof(_Float16);   // 4 MiB
  const size_t nCsq = (size_t)K_CENT * sizeof(float);           // 16 KiB
  const int grid = N_ROWS / TILE_M;                              // 512 blocks

  if (ws_size >= nXh + nCh + nCsq) {
    _Float16* xh = (_Float16*)d_ws;
    _Float16* ch = (_Float16*)((char*)d_ws + nXh);
    float* csqg = (float*)((char*)d_ws + nXh + nCh);
    const size_t total8 = ((size_t)N_ROWS + K_CENT) * DIM / 8;
    prep_convert<<<(unsigned)((total8 + 255) / 256), 256, 0, stream>>>(x, cent, xh, ch);
    prep_csq<<<(K_CENT * 64) / 256, 256, 0, stream>>>(ch, csqg);
    kmeans_argmin<2><<<grid, THREADS, 0, stream>>>(x, cent, xh, ch, csqg, out);
  } else if (ws_size >= nXh + nCh) {
    _Float16* xh = (_Float16*)d_ws;
    _Float16* ch = (_Float16*)((char*)d_ws + nXh);
    const size_t total8 = ((size_t)N_ROWS + K_CENT) * DIM / 8;
    prep_convert<<<(unsigned)((total8 + 255) / 256), 256, 0, stream>>>(x, cent, xh, ch);
    kmeans_argmin<1><<<grid, THREADS, 0, stream>>>(x, cent, xh, ch, nullptr, out);
  } else {
    kmeans_argmin<0><<<grid, THREADS, 0, stream>>>(x, cent, nullptr, nullptr, nullptr, out);
  }
}

// Round 3
// 683.006 us; speedup vs baseline: 1.6734x; 1.0844x over previous
//
#include <hip/hip_runtime.h>

#define N_ROWS 65536
#define DIM    512
#define K_CENT 4096
#define TILE_M 128
#define TILE_N 256
#define BK     32
#define KSTEPS (DIM / BK)        // 16
#define NKT    (K_CENT / TILE_N) // 16
#define THREADS 512
#define MARGIN 6.0f
#define CAND_CAP 3072
#define COMPACT_TRIG 2048

typedef _Float16 half8 __attribute__((ext_vector_type(8)));
typedef float floatx4 __attribute__((ext_vector_type(4)));

// order-preserving float<->uint map
__device__ __forceinline__ unsigned mapF(float f) {
  unsigned u = __float_as_uint(f);
  return (u & 0x80000000u) ? ~u : (u | 0x80000000u);
}
__device__ __forceinline__ float unmapF(unsigned m) {
  unsigned u = (m & 0x80000000u) ? (m ^ 0x80000000u) : ~m;
  return __uint_as_float(u);
}

__device__ __forceinline__ void gload_lds16(const void* g, void* l) {
  __builtin_amdgcn_global_load_lds(
      (const __attribute__((address_space(1))) void*)g,
      (__attribute__((address_space(3))) void*)l, 16, 0, 0);
}

// fp32 -> fp16 conversion for x and center; csq (||c_fp16||^2) fused into the
// center branch (each 64-lane wave covers exactly one 512-dim center row).
__global__ void prep_convert(const float* __restrict__ x, const float* __restrict__ c,
                             _Float16* __restrict__ xh, _Float16* __restrict__ ch,
                             float* __restrict__ csqg) {
  const size_t nx = (size_t)N_ROWS * DIM;
  const size_t nc = (size_t)K_CENT * DIM;
  size_t i = ((size_t)blockIdx.x * blockDim.x + threadIdx.x) * 8;
  if (i >= nx + nc) return;
  if (i < nx) {
    floatx4 a = *(const floatx4*)(x + i);
    floatx4 b = *(const floatx4*)(x + i + 4);
    half8 h;
#pragma unroll
    for (int e = 0; e < 4; ++e) { h[e] = (_Float16)a[e]; h[4 + e] = (_Float16)b[e]; }
    *(half8*)(xh + i) = h;
  } else {
    size_t off = i - nx;
    floatx4 a = *(const floatx4*)(c + off);
    floatx4 b = *(const floatx4*)(c + off + 4);
    half8 h;
    float s = 0.f;
#pragma unroll
    for (int e = 0; e < 4; ++e) { h[e] = (_Float16)a[e]; h[4 + e] = (_Float16)b[e]; }
#pragma unroll
    for (int e = 0; e < 8; ++e) { float v = (float)h[e]; s += v * v; }
    *(half8*)(ch + off) = h;
#pragma unroll
    for (int o = 1; o < 64; o <<= 1) s += __shfl_xor(s, o, 64);
    if ((threadIdx.x & 63) == 0) csqg[off >> 9] = s;
  }
}

// MODE 0: no ws (fp32 loads, on-the-fly convert, LDS csq)
// MODE 2: fp16 pre-converted + precomputed csq in ws
//
// 512 threads = 8 waves (2 wave-rows x 4 wave-cols), block tile 128x256,
// wave tile 64x64 (16 MFMA / ks / wave), 16x16x32 f16 MFMA, BK=32.
// Single pass over K: per kt, tighten the per-row running min FIRST
// (shfl-pre-reduced, then 512 LDS atomicMins), barrier, then collect
// candidates against runmin+MARGIN (superset of final within-MARGIN set).
// fp64-exact refine of survivors at the end.
// XOR chunk swizzle ((row>>1)&3) keeps ds_read_b128 at <=2-way conflicts
// while staying compatible with global_load_lds lane-contiguous dst.
template <int MODE>
__global__ __launch_bounds__(THREADS, 4)
void kmeans_argmin(const float* __restrict__ x, const float* __restrict__ cent,
                   const _Float16* __restrict__ xh, const _Float16* __restrict__ ch,
                   const float* __restrict__ csqg, int* __restrict__ out) {
  __shared__ _Float16 ldsA[TILE_M * BK];        // 8 KB
  __shared__ _Float16 ldsB[TILE_N * BK];        // 16 KB
  __shared__ float csq4[TILE_N][4];             // 4 KB (MODE 0 only)
  __shared__ unsigned sminU[TILE_M];
  __shared__ unsigned long long best[TILE_M];
  __shared__ unsigned candKey[CAND_CAP];
  __shared__ float candS[CAND_CAP];
  __shared__ int candCount;

  char* ldsAc = (char*)ldsA;
  char* ldsBc = (char*)ldsB;

  const int t = threadIdx.x;
  const int lane = t & 63;
  const int wave = t >> 6;   // 0..7
  const int wm = wave >> 2;  // 0..1 row-waves
  const int wn = wave & 3;   // 0..3 col-waves
  const int quad = lane >> 4;
  const int l15 = lane & 15;
  const int rowBlock = blockIdx.x * TILE_M;

  if (t < TILE_M) { sminU[t] = 0xFFFFFFFFu; best[t] = ~0ull; }
  if (t == 0) candCount = 0;

  // staging: thread t owns A slot t; B slots t and t+512. swizzled source chunk.
  const int srA = t >> 2;
  const int sckA = (t & 3) ^ ((srA >> 1) & 3);
  const int srB0 = t >> 2;             // slot t
  const int srB1 = (t + 512) >> 2;     // slot t+512
  const int sckB0 = (t & 3) ^ ((srB0 >> 1) & 3);
  const int sckB1 = (t & 3) ^ ((srB1 >> 1) & 3);

  for (int kt = 0; kt < NKT; ++kt) {
    const int ktBase = kt * TILE_N;
    if (MODE == 0) { ((float*)csq4)[t] = 0.f; ((float*)csq4)[t + 512] = 0.f; }
    floatx4 acc[4][4];
#pragma unroll
    for (int fm = 0; fm < 4; ++fm)
#pragma unroll
      for (int fn = 0; fn < 4; ++fn) acc[fm][fn] = (floatx4){0.f, 0.f, 0.f, 0.f};

    for (int ks = 0; ks < KSTEPS; ++ks) {
      const int kd = ks * BK;
      if (MODE == 2) {
        gload_lds16(xh + (size_t)(rowBlock + srA) * DIM + kd + sckA * 8,
                    ldsAc + (size_t)wave * 1024);
        gload_lds16(ch + (size_t)(ktBase + srB0) * DIM + kd + sckB0 * 8,
                    ldsBc + (size_t)wave * 1024);
        gload_lds16(ch + (size_t)(ktBase + srB1) * DIM + kd + sckB1 * 8,
                    ldsBc + 8192 + (size_t)wave * 1024);
      } else {
        const float* gA = x + (size_t)(rowBlock + srA) * DIM + kd + sckA * 8;
        floatx4 a0 = *(const floatx4*)gA, a1 = *(const floatx4*)(gA + 4);
        half8 ha;
#pragma unroll
        for (int e = 0; e < 4; ++e) { ha[e] = (_Float16)a0[e]; ha[4 + e] = (_Float16)a1[e]; }
        *(half8*)(ldsAc + (size_t)t * 16) = ha;
#pragma unroll
        for (int p = 0; p < 2; ++p) {
          int sr = p ? srB1 : srB0;
          int sck = p ? sckB1 : sckB0;
          int slot = p * 512 + t;
          const float* gB = cent + (size_t)(ktBase + sr) * DIM + kd + sck * 8;
          floatx4 b0 = *(const floatx4*)gB, b1 = *(const floatx4*)(gB + 4);
          half8 hb;
          float s = 0.f;
#pragma unroll
          for (int e = 0; e < 4; ++e) { hb[e] = (_Float16)b0[e]; hb[4 + e] = (_Float16)b1[e]; }
#pragma unroll
          for (int e = 0; e < 8; ++e) { float v = (float)hb[e]; s += v * v; }
          *(half8*)(ldsBc + (size_t)slot * 16) = hb;
          csq4[sr][slot & 3] += s;
        }
      }
      __syncthreads();

      half8 af[4], bf[4];
#pragma unroll
      for (int fm = 0; fm < 4; ++fm) {
        int row = wm * 64 + fm * 16 + l15;
        int slot = (row << 2) | (quad ^ ((row >> 1) & 3));
        af[fm] = *(const half8*)(ldsAc + slot * 16);
      }
#pragma unroll
      for (int fn = 0; fn < 4; ++fn) {
        int cl = wn * 64 + fn * 16 + l15;
        int slot = (cl << 2) | (quad ^ ((cl >> 1) & 3));
        bf[fn] = *(const half8*)(ldsBc + slot * 16);
      }
#pragma unroll
      for (int fm = 0; fm < 4; ++fm)
#pragma unroll
        for (int fn = 0; fn < 4; ++fn)
          acc[fm][fn] = __builtin_amdgcn_mfma_f32_16x16x32_f16(af[fm], bf[fn], acc[fm][fn], 0, 0, 0);
      __syncthreads();
    }

    // ---- epilogue: s = ||c||^2 - 2*cross (||x||^2 constant per row, dropped)
    // C layout 16x16: col = lane&15, row = quad*4 + e  [m89-verified]
    float cs[4];
#pragma unroll
    for (int fn = 0; fn < 4; ++fn) {
      int cl = wn * 64 + fn * 16 + l15;
      cs[fn] = (MODE == 2) ? csqg[ktBase + cl]
                           : (csq4[cl][0] + csq4[cl][1] + csq4[cl][2] + csq4[cl][3]);
    }

    // tighten running min FIRST (shfl pre-reduce over the 16 lanes sharing rows)
#pragma unroll
    for (int fm = 0; fm < 4; ++fm)
#pragma unroll
      for (int e = 0; e < 4; ++e) {
        float v = 3.4e38f;
#pragma unroll
        for (int fn = 0; fn < 4; ++fn)
          v = fminf(v, cs[fn] - 2.f * acc[fm][fn][e]);
        v = fminf(v, __shfl_xor(v, 1, 64));
        v = fminf(v, __shfl_xor(v, 2, 64));
        v = fminf(v, __shfl_xor(v, 4, 64));
        v = fminf(v, __shfl_xor(v, 8, 64));
        if (l15 == 0)
          atomicMin(&sminU[wm * 64 + fm * 16 + quad * 4 + e], mapF(v));
      }
    __syncthreads();

    float thrR[4][4];
#pragma unroll
    for (int fm = 0; fm < 4; ++fm)
#pragma unroll
      for (int e = 0; e < 4; ++e)
        thrR[fm][e] = unmapF(sminU[wm * 64 + fm * 16 + quad * 4 + e]) + MARGIN;

    // collect against the tightened (still prefix, hence superset) threshold
#pragma unroll
    for (int fn = 0; fn < 4; ++fn) {
      int k = ktBase + wn * 64 + fn * 16 + l15;
#pragma unroll
      for (int fm = 0; fm < 4; ++fm)
#pragma unroll
        for (int e = 0; e < 4; ++e) {
          float s = cs[fn] - 2.f * acc[fm][fn][e];
          if (s <= thrR[fm][e]) {
            int idx = atomicAdd(&candCount, 1);
            if (idx < CAND_CAP) {
              candKey[idx] = ((unsigned)k << 7) | (unsigned)(wm * 64 + fm * 16 + quad * 4 + e);
              candS[idx] = s;
            }
          }
        }
    }
    __syncthreads();

    // compaction backstop against tightened threshold (rarely triggers)
    if (candCount > COMPACT_TRIG) {
      int cc = candCount; if (cc > CAND_CAP) cc = CAND_CAP;
      unsigned myK[6]; float myS[6]; int myN = 0;
      for (int i = t; i < cc; i += THREADS) {
        int rl = candKey[i] & 127;
        if (candS[i] <= unmapF(sminU[rl]) + MARGIN) {
          myK[myN] = candKey[i]; myS[myN] = candS[i]; ++myN;
        }
      }
      __syncthreads();
      if (t == 0) candCount = 0;
      __syncthreads();
      int base = atomicAdd(&candCount, myN);
      for (int j = 0; j < myN; ++j) { candKey[base + j] = myK[j]; candS[base + j] = myS[j]; }
      __syncthreads();
    }
  }

  // ---- fp64-exact refinement of surviving candidates (original fp32 inputs)
  int cnt = candCount; if (cnt > CAND_CAP) cnt = CAND_CAP;
  const int g = t >> 4;   // 32 groups of 16 lanes
  const int sl = t & 15;
  for (int ci = g; ci < cnt; ci += 32) {
    unsigned cd = candKey[ci];
    int rl = cd & 127;
    if (candS[ci] > unmapF(sminU[rl]) + MARGIN) continue;  // group-uniform branch
    int k = cd >> 7;
    const float* xr = x + (size_t)(rowBlock + rl) * DIM;
    const float* cr = cent + (size_t)k * DIM;
    double d = 0.0;
#pragma unroll
    for (int j = 0; j < DIM / 64; ++j) {
      floatx4 xv = *(const floatx4*)(xr + j * 64 + sl * 4);
      floatx4 cv = *(const floatx4*)(cr + j * 64 + sl * 4);
#pragma unroll
      for (int e = 0; e < 4; ++e) {
        double df = (double)xv[e] - (double)cv[e];
        d += df * df;
      }
    }
#pragma unroll
    for (int off = 1; off < 16; off <<= 1) d += __shfl_xor(d, off, 64);
    if (sl == 0) {
      // positive doubles order as uint64; low 12 mantissa bits -> index (ties: lower k)
      unsigned long long key =
          ((unsigned long long)__double_as_longlong(d) & ~0xFFFull) | (unsigned long long)k;
      atomicMin(&best[rl], key);
    }
  }
  __syncthreads();
  if (t < TILE_M) out[rowBlock + t] = (int)(best[t] & 0xFFFull);
}

extern "C" void kernel_launch(void* const* d_in, const int* in_sizes, int n_in,
                              void* d_out, int out_size, void* d_ws, size_t ws_size,
                              hipStream_t stream) {
  const float* x = (const float*)d_in[0];
  const float* cent = (const float*)d_in[1];
  int* out = (int*)d_out;
  const size_t nXh = (size_t)N_ROWS * DIM * sizeof(_Float16);   // 64 MiB
  const size_t nCh = (size_t)K_CENT * DIM * sizeof(_Float16);   // 4 MiB
  const size_t nCsq = (size_t)K_CENT * sizeof(float);           // 16 KiB
  const int grid = N_ROWS / TILE_M;                              // 512 blocks

  if (ws_size >= nXh + nCh + nCsq) {
    _Float16* xh = (_Float16*)d_ws;
    _Float16* ch = (_Float16*)((char*)d_ws + nXh);
    float* csqg = (float*)((char*)d_ws + nXh + nCh);
    const size_t total8 = ((size_t)N_ROWS + K_CENT) * DIM / 8;
    prep_convert<<<(unsigned)((total8 + 255) / 256), 256, 0, stream>>>(x, cent, xh, ch, csqg);
    kmeans_argmin<2><<<grid, THREADS, 0, stream>>>(x, cent, xh, ch, csqg, out);
  } else {
    kmeans_argmin<0><<<grid, THREADS, 0, stream>>>(x, cent, nullptr, nullptr, nullptr, out);
  }
}